// Round 1
// baseline (121.067 us; speedup 1.0000x reference)
//
// Fused 3-bit dequant GEMM: C[64,11008] = A[64,4096] @ ((q-4) * s[group])
// Strategy: pre-convert A to bf16 row-major A' in d_ws (one tiny kernel), then
// a streaming MFMA kernel: 688 blocks x 1 wave; each wave owns 16 output
// columns and all 64 rows (4x mfma_f32_16x16x32_bf16 per 32-k step).
// q (180 MB int32) is the HBM-bound stream: read once, nontemporal, in 64B
// segments per 16-lane group, register-double-buffered 2 chunks (128 k) deep.
// A' (512 KB) stays L2-resident; no LDS, no barriers.
// Predicted: ~186 MB fetch -> ~30-40 us, HBM-bound.

#include <hip/hip_runtime.h>

#define K_ 4096
#define N_ 11008
#define NBLK (N_ / 16)          // 688 blocks
#define ZEROPT 4

typedef __attribute__((ext_vector_type(8))) short bf16x8;
typedef __attribute__((ext_vector_type(4))) float f32x4;
typedef __attribute__((ext_vector_type(4))) unsigned uint4v;
typedef __attribute__((ext_vector_type(2))) unsigned uint2v;
typedef __attribute__((ext_vector_type(4))) float float4v;

static __device__ __forceinline__ unsigned rne_bits(float f) {
  unsigned u = __builtin_bit_cast(unsigned, f);
  return u + 0x7fffu + ((u >> 16) & 1u);   // bf16 in bits [31:16], round-nearest-even
}
static __device__ __forceinline__ unsigned pack_bf16(float lo, float hi) {
  return (rne_bits(hi) & 0xffff0000u) | (rne_bits(lo) >> 16);
}

// A (64x4096 f32, row-major) -> A' (bf16, same layout). 256 blocks x 256 thr x 4 elems.
__global__ __launch_bounds__(256) void cvtA_kernel(const float* __restrict__ A,
                                                   unsigned* __restrict__ Ap) {
  const int i = (blockIdx.x * 256 + threadIdx.x) * 4;
  float4v v = *reinterpret_cast<const float4v*>(A + i);
  uint2v o = { pack_bf16(v[0], v[1]), pack_bf16(v[2], v[3]) };
  *reinterpret_cast<uint2v*>(Ap + (i >> 1)) = o;
}

template <bool FROM_BF16>
__global__ __launch_bounds__(64) void dq_gemm_kernel(
    const int* __restrict__ q, const float* __restrict__ s,
    const short* __restrict__ Ap, const float* __restrict__ Af,
    float* __restrict__ out) {
  const int l    = threadIdx.x;
  const int fr   = l & 15;        // MFMA 16-index: A row / B col / D col
  const int lg   = l >> 4;        // k-group 0..3
  const int n    = blockIdx.x * 16 + fr;
  const int kofs = lg * 8;

  const int* qp = q + (size_t)kofs * N_ + n;

  f32x4 acc[4] = {f32x4{0,0,0,0}, f32x4{0,0,0,0}, f32x4{0,0,0,0}, f32x4{0,0,0,0}};

  int qbA[16], qbB[16];           // named double buffers (no runtime indexing -> no scratch)
  float scA, scB;

  auto load_chunk = [&](int kc, int* dst) {
    #pragma unroll
    for (int t = 0; t < 2; ++t)
      #pragma unroll
      for (int i = 0; i < 8; ++i)
        dst[t * 8 + i] =
            __builtin_nontemporal_load(qp + (size_t)(kc + t * 32 + i) * N_);
  };

  auto load_afrag = [&](int mt, int k) -> bf16x8 {
    if constexpr (FROM_BF16) {
      return *reinterpret_cast<const bf16x8*>(Ap + (size_t)(mt * 16 + fr) * K_ + k);
    } else {
      const float* ap = Af + (size_t)(mt * 16 + fr) * K_ + k;
      float4v v0 = *reinterpret_cast<const float4v*>(ap);
      float4v v1 = *reinterpret_cast<const float4v*>(ap + 4);
      uint4v b = { pack_bf16(v0[0], v0[1]), pack_bf16(v0[2], v0[3]),
                   pack_bf16(v1[0], v1[1]), pack_bf16(v1[2], v1[3]) };
      return __builtin_bit_cast(bf16x8, b);
    }
  };

  auto compute_chunk = [&](int kc, const int* qb, float sc) {
    const float sneg = -(float)ZEROPT * sc;   // fma(q, s, -4s) == round((q-4)*s)
    #pragma unroll
    for (int t = 0; t < 2; ++t) {
      unsigned pk[4];
      #pragma unroll
      for (int p = 0; p < 4; ++p) {
        float w0 = fmaf((float)qb[t * 8 + 2 * p + 0], sc, sneg);
        float w1 = fmaf((float)qb[t * 8 + 2 * p + 1], sc, sneg);
        pk[p] = pack_bf16(w0, w1);
      }
      uint4v bv = {pk[0], pk[1], pk[2], pk[3]};
      bf16x8 bfrag = __builtin_bit_cast(bf16x8, bv);
      #pragma unroll
      for (int mt = 0; mt < 4; ++mt) {
        bf16x8 afrag = load_afrag(mt, kc + t * 32 + kofs);
        acc[mt] = __builtin_amdgcn_mfma_f32_16x16x32_bf16(afrag, bfrag, acc[mt],
                                                          0, 0, 0);
      }
    }
  };

  // ---- K loop: two 64-k chunks per iteration, register double-buffered ----
  load_chunk(0, qbA);
  scA = s[n];                                  // group 0 scale for this column

  for (int kc = 0; kc < K_; kc += 128) {
    load_chunk(kc + 64, qbB);
    scB = s[(size_t)((kc >> 6) + 1) * N_ + n];
    compute_chunk(kc, qbA, scA);
    if (kc + 128 < K_) {
      load_chunk(kc + 128, qbA);
      scA = s[(size_t)((kc >> 6) + 2) * N_ + n];
    }
    compute_chunk(kc + 64, qbB, scB);
  }

  // ---- epilogue: D row = (lane>>4)*4 + j, col = lane&15 ----
  #pragma unroll
  for (int mt = 0; mt < 4; ++mt)
    #pragma unroll
    for (int j = 0; j < 4; ++j)
      __builtin_nontemporal_store(
          acc[mt][j], out + (size_t)(mt * 16 + lg * 4 + j) * N_ + n);
}

extern "C" void kernel_launch(void* const* d_in, const int* in_sizes, int n_in,
                              void* d_out, int out_size, void* d_ws, size_t ws_size,
                              hipStream_t stream) {
  const float* A = (const float*)d_in[0];
  const int*   q = (const int*)d_in[1];
  const float* s = (const float*)d_in[2];
  float* out = (float*)d_out;

  const size_t apBytes = (size_t)64 * K_ * sizeof(short);   // 512 KB
  if (ws_size >= apBytes) {
    short* Ap = (short*)d_ws;
    hipLaunchKernelGGL(cvtA_kernel, dim3((64 * K_) / 1024), dim3(256), 0, stream,
                       A, (unsigned*)Ap);
    hipLaunchKernelGGL((dq_gemm_kernel<true>), dim3(NBLK), dim3(64), 0, stream,
                       q, s, Ap, A, out);
  } else {
    hipLaunchKernelGGL((dq_gemm_kernel<false>), dim3(NBLK), dim3(64), 0, stream,
                       q, s, (const short*)nullptr, A, out);
  }
}

// Round 2
// 115.519 us; speedup vs baseline: 1.0480x; 1.0480x over previous
//
// Fused 3-bit dequant GEMM: C[64,11008] = A[64,4096] @ ((q-4) * s[group])
// R2: K-split 8 waves/block to fix latency-bound starvation (R1: occ 6.7%,
// 1.56 TB/s). 688 blocks x 512 threads; wave w handles k in [w*512,(w+1)*512)
// for the block's 16 columns, register-double-buffered q loads (nontemporal),
// 4x mfma_f32_16x16x32_bf16 per 32-k step. One LDS reduction (pad-17, free
// bank-wise) + one barrier combines the 8 partials; coalesced 64B row stores.
// A' (bf16, 512 KB in d_ws) stays L2-resident. Predicted ~32-40 us, ~75-90% HBM.

#include <hip/hip_runtime.h>

#define K_ 4096
#define N_ 11008
#define NBLK (N_ / 16)          // 688 blocks
#define ZEROPT 4

typedef __attribute__((ext_vector_type(8))) short bf16x8;
typedef __attribute__((ext_vector_type(4))) float f32x4;
typedef __attribute__((ext_vector_type(4))) unsigned uint4v;
typedef __attribute__((ext_vector_type(2))) unsigned uint2v;
typedef __attribute__((ext_vector_type(4))) float float4v;

static __device__ __forceinline__ unsigned rne_bits(float f) {
  unsigned u = __builtin_bit_cast(unsigned, f);
  return u + 0x7fffu + ((u >> 16) & 1u);   // bf16 in bits [31:16], RNE
}
static __device__ __forceinline__ unsigned pack_bf16(float lo, float hi) {
  return (rne_bits(hi) & 0xffff0000u) | (rne_bits(lo) >> 16);
}

// A (64x4096 f32, row-major) -> A' (bf16, same layout). 64 blocks x 256 thr x 4 elems.
__global__ __launch_bounds__(256) void cvtA_kernel(const float* __restrict__ A,
                                                   unsigned* __restrict__ Ap) {
  const int i = (blockIdx.x * 256 + threadIdx.x) * 4;
  float4v v = *reinterpret_cast<const float4v*>(A + i);
  uint2v o = { pack_bf16(v[0], v[1]), pack_bf16(v[2], v[3]) };
  *reinterpret_cast<uint2v*>(Ap + (i >> 1)) = o;
}

template <int NW, bool FROM_BF16>
__global__ __launch_bounds__(NW * 64) void dq_gemm_kernel(
    const int* __restrict__ q, const float* __restrict__ s,
    const short* __restrict__ Ap, const float* __restrict__ Af,
    float* __restrict__ out) {
  const int tid  = threadIdx.x;
  const int l    = tid & 63;
  const int w    = tid >> 6;      // wave id 0..NW-1 (K-slice owner)
  const int fr   = l & 15;        // MFMA 16-index: A row / B col / D col
  const int lg   = l >> 4;        // k-group 0..3
  const int n0   = blockIdx.x * 16;
  const int n    = n0 + fr;
  const int kofs = lg * 8;

  constexpr int KSEG = K_ / NW;   // 512 for NW=8; must be %128==0
  static_assert(KSEG % 128 == 0, "K slice must cover whole double-buffer iters");
  const int base = w * KSEG;

  const int* qp = q + (size_t)kofs * N_ + n;

  f32x4 acc[4] = {f32x4{0,0,0,0}, f32x4{0,0,0,0}, f32x4{0,0,0,0}, f32x4{0,0,0,0}};

  int qbA[16], qbB[16];           // named double buffers (no runtime indexing)
  float scA, scB;

  auto load_chunk = [&](int kc, int* dst) {   // kc: global k, multiple of 64
    #pragma unroll
    for (int t = 0; t < 2; ++t)
      #pragma unroll
      for (int i = 0; i < 8; ++i)
        dst[t * 8 + i] =
            __builtin_nontemporal_load(qp + (size_t)(kc + t * 32 + i) * N_);
  };

  auto load_afrag = [&](int mt, int k) -> bf16x8 {
    if constexpr (FROM_BF16) {
      return *reinterpret_cast<const bf16x8*>(Ap + (size_t)(mt * 16 + fr) * K_ + k);
    } else {
      const float* ap = Af + (size_t)(mt * 16 + fr) * K_ + k;
      float4v v0 = *reinterpret_cast<const float4v*>(ap);
      float4v v1 = *reinterpret_cast<const float4v*>(ap + 4);
      uint4v b = { pack_bf16(v0[0], v0[1]), pack_bf16(v0[2], v0[3]),
                   pack_bf16(v1[0], v1[1]), pack_bf16(v1[2], v1[3]) };
      return __builtin_bit_cast(bf16x8, b);
    }
  };

  auto compute_chunk = [&](int kc, const int* qb, float sc) {
    const float sneg = -(float)ZEROPT * sc;   // fma(q, s, -4s) == (q-4)*s
    #pragma unroll
    for (int t = 0; t < 2; ++t) {
      unsigned pk[4];
      #pragma unroll
      for (int p = 0; p < 4; ++p) {
        float w0 = fmaf((float)qb[t * 8 + 2 * p + 0], sc, sneg);
        float w1 = fmaf((float)qb[t * 8 + 2 * p + 1], sc, sneg);
        pk[p] = pack_bf16(w0, w1);
      }
      uint4v bv = {pk[0], pk[1], pk[2], pk[3]};
      bf16x8 bfrag = __builtin_bit_cast(bf16x8, bv);
      #pragma unroll
      for (int mt = 0; mt < 4; ++mt) {
        bf16x8 afrag = load_afrag(mt, kc + t * 32 + kofs);
        acc[mt] = __builtin_amdgcn_mfma_f32_16x16x32_bf16(afrag, bfrag, acc[mt],
                                                          0, 0, 0);
      }
    }
  };

  // ---- K loop over this wave's slice: two 64-k chunks/iter, reg dbuf ----
  load_chunk(base, qbA);
  scA = s[(size_t)(base >> 6) * N_ + n];

  for (int kk = 0; kk < KSEG; kk += 128) {
    const int kc = base + kk;
    load_chunk(kc + 64, qbB);
    scB = s[(size_t)((kc >> 6) + 1) * N_ + n];
    compute_chunk(kc, qbA, scA);
    if (kk + 128 < KSEG) {
      load_chunk(kc + 128, qbA);
      scA = s[(size_t)((kc >> 6) + 2) * N_ + n];
    }
    compute_chunk(kc + 64, qbB, scB);
  }

  // ---- cross-wave reduction in LDS (pad 17 -> 2 lanes/bank = free) ----
  __shared__ float red[NW][64 * 17];
  #pragma unroll
  for (int mt = 0; mt < 4; ++mt)
    #pragma unroll
    for (int j = 0; j < 4; ++j)
      red[w][l * 17 + mt * 4 + j] = acc[mt][j];
  __syncthreads();

  // 1024 outputs (64 rows x 16 cols), NW*64 threads -> 1024/(NW*64) each.
  // Map o = rr*16 + c so each 16-lane group stores a 64B row segment.
  #pragma unroll
  for (int rep = 0; rep < 1024 / (NW * 64); ++rep) {
    const int o  = tid + rep * NW * 64;
    const int c  = o & 15;
    const int rr = o >> 4;                       // output row 0..63
    const int li = ((rr >> 2) & 3) * 16 + c;     // source lane
    const int ii = ((rr >> 4) << 2) | (rr & 3);  // source acc index
    float sum = 0.f;
    #pragma unroll
    for (int ww = 0; ww < NW; ++ww) sum += red[ww][li * 17 + ii];
    __builtin_nontemporal_store(sum, out + (size_t)rr * N_ + n0 + c);
  }
}

extern "C" void kernel_launch(void* const* d_in, const int* in_sizes, int n_in,
                              void* d_out, int out_size, void* d_ws, size_t ws_size,
                              hipStream_t stream) {
  const float* A = (const float*)d_in[0];
  const int*   q = (const int*)d_in[1];
  const float* s = (const float*)d_in[2];
  float* out = (float*)d_out;

  constexpr int NW = 8;   // waves per block (K-split factor)
  const size_t apBytes = (size_t)64 * K_ * sizeof(short);   // 512 KB
  if (ws_size >= apBytes) {
    short* Ap = (short*)d_ws;
    hipLaunchKernelGGL(cvtA_kernel, dim3((64 * K_) / 1024), dim3(256), 0, stream,
                       A, (unsigned*)Ap);
    hipLaunchKernelGGL((dq_gemm_kernel<NW, true>), dim3(NBLK), dim3(NW * 64), 0,
                       stream, q, s, Ap, A, out);
  } else {
    hipLaunchKernelGGL((dq_gemm_kernel<NW, false>), dim3(NBLK), dim3(NW * 64), 0,
                       stream, q, s, (const short*)nullptr, A, out);
  }
}

// Round 3
// 55.033 us; speedup vs baseline: 2.1999x; 2.0991x over previous
//
// Fused 3-bit dequant GEMM: C[64,11008] = A[64,4096] @ ((q-4) * s[group])
// R3: fix DRAM page locality. R1/R2 read q in scattered 64B strips (stride
// 44KB) -> ~1.6 TB/s ceiling regardless of occupancy. Now each block stages a
// [32 k][256 n] q tile into LDS with global_load_lds dwordx4 — one contiguous
// 1KB row per wave-instruction — and 8 waves dequant+MFMA from LDS.
// Grid = 43 col-chunks x 16 k-bands; bf16 partials in d_ws + reduce kernel
// (deterministic). LDS 33KB, launch_bounds(512,6) -> 3 blocks/CU -> all 688
// blocks resident. Fallback: atomicAdd epilogue if ws too small.
// Predicted: ~4.5-6 TB/s on the q stream, ~38-48 us total.

#include <hip/hip_runtime.h>

#define K_ 4096
#define N_ 11008
#define M_ 64
#define SB 16                  // k-split factor (bands of 256)
#define CB 43                  // column chunks of 256
#define BK 32                  // k rows per LDS tile
#define BN 256                 // columns per block
#define KBAND (K_ / SB)        // 256
#define LDS_PITCH 260          // int32 pitch per row (1040B, 16B-aligned)

typedef __attribute__((ext_vector_type(8))) short bf16x8;
typedef __attribute__((ext_vector_type(4))) float f32x4;
typedef __attribute__((ext_vector_type(4))) unsigned uint4v;
typedef __attribute__((ext_vector_type(2))) unsigned uint2v;
typedef __attribute__((ext_vector_type(4))) float float4v;
typedef __attribute__((ext_vector_type(4))) unsigned short ushort4v;

static __device__ __forceinline__ unsigned rne_bits(float f) {
  unsigned u = __builtin_bit_cast(unsigned, f);
  return u + 0x7fffu + ((u >> 16) & 1u);   // bf16 in bits [31:16], RNE
}
static __device__ __forceinline__ unsigned pack_bf16(float lo, float hi) {
  return (rne_bits(hi) & 0xffff0000u) | (rne_bits(lo) >> 16);
}
static __device__ __forceinline__ unsigned short bf16_1(float f) {
  return (unsigned short)(rne_bits(f) >> 16);
}

// A (64x4096 f32, row-major) -> A' (bf16, same layout). 256 blocks x 256 thr.
__global__ __launch_bounds__(256) void cvtA_kernel(const float* __restrict__ A,
                                                   unsigned* __restrict__ Ap) {
  const int i = (blockIdx.x * 256 + threadIdx.x) * 4;
  float4v v = *reinterpret_cast<const float4v*>(A + i);
  uint2v o = { pack_bf16(v[0], v[1]), pack_bf16(v[2], v[3]) };
  *reinterpret_cast<uint2v*>(Ap + (i >> 1)) = o;
}

template <bool FROM_BF16, bool ATOMIC>
__global__ __launch_bounds__(512, 6) void dq_gemm_kernel(
    const int* __restrict__ q, const float* __restrict__ s,
    const short* __restrict__ Ap, const float* __restrict__ Af,
    unsigned short* __restrict__ P, float* __restrict__ out) {
  __shared__ int tile[BK * LDS_PITCH];   // 33,280 B

  const int tid = threadIdx.x;
  const int l  = tid & 63;
  const int w  = tid >> 6;        // wave 0..7 (owns 32 columns)
  const int fr = l & 15;
  const int lg = l >> 4;
  const int cb = blockIdx.x % CB; // column chunk (fastest -> adjacent blocks
  const int sb = blockIdx.x / CB; //  read adjacent 1KB stretches)
  const int n0 = cb * BN;
  const int k0 = sb * KBAND;
  const int colw = w * 32;

  f32x4 acc[4][2];
  #pragma unroll
  for (int mt = 0; mt < 4; ++mt)
    #pragma unroll
    for (int nt = 0; nt < 2; ++nt)
      acc[mt][nt] = f32x4{0.f, 0.f, 0.f, 0.f};

  for (int st = 0; st < KBAND / BK; ++st) {
    const int kst = k0 + st * BK;

    // ---- stage [32][256] int32 tile: 1KB contiguous per wave-instruction ----
    #pragma unroll
    for (int r = 0; r < 4; ++r) {
      const int row = r * 8 + w;                       // wave-uniform
      const int* gp = q + (size_t)(kst + row) * N_ + n0 + l * 4;
      __builtin_amdgcn_global_load_lds(
          (const __attribute__((address_space(1))) unsigned*)gp,
          (__attribute__((address_space(3))) unsigned*)&tile[row * LDS_PITCH],
          16, 0, 0);
    }

    const int g = kst >> 6;                            // scale group
    const float sc0 = s[(size_t)g * N_ + n0 + colw + fr];
    const float sc1 = s[(size_t)g * N_ + n0 + colw + 16 + fr];

    __syncthreads();   // barrier drains vmcnt -> tile visible to all waves

    // ---- A fragments (L2-resident) ----
    bf16x8 af[4];
    #pragma unroll
    for (int mt = 0; mt < 4; ++mt) {
      if constexpr (FROM_BF16) {
        af[mt] = *reinterpret_cast<const bf16x8*>(
            Ap + (size_t)(mt * 16 + fr) * K_ + kst + 8 * lg);
      } else {
        const float* ap = Af + (size_t)(mt * 16 + fr) * K_ + kst + 8 * lg;
        float4v v0 = *reinterpret_cast<const float4v*>(ap);
        float4v v1 = *reinterpret_cast<const float4v*>(ap + 4);
        uint4v b = { pack_bf16(v0[0], v0[1]), pack_bf16(v0[2], v0[3]),
                     pack_bf16(v1[0], v1[1]), pack_bf16(v1[2], v1[3]) };
        af[mt] = __builtin_bit_cast(bf16x8, b);
      }
    }

    // ---- dequant + MFMA: wave w covers cols [colw, colw+32) ----
    #pragma unroll
    for (int nt = 0; nt < 2; ++nt) {
      const int col = colw + nt * 16 + fr;
      const float sc = nt ? sc1 : sc0;
      const float sn = -4.0f * sc;                     // fma(q, s, -4s)
      unsigned pk[4];
      #pragma unroll
      for (int p = 0; p < 4; ++p) {
        const int c0 = tile[(8 * lg + 2 * p + 0) * LDS_PITCH + col];
        const int c1 = tile[(8 * lg + 2 * p + 1) * LDS_PITCH + col];
        pk[p] = pack_bf16(fmaf((float)c0, sc, sn), fmaf((float)c1, sc, sn));
      }
      uint4v bv = {pk[0], pk[1], pk[2], pk[3]};
      const bf16x8 bfrag = __builtin_bit_cast(bf16x8, bv);
      #pragma unroll
      for (int mt = 0; mt < 4; ++mt)
        acc[mt][nt] = __builtin_amdgcn_mfma_f32_16x16x32_bf16(
            af[mt], bfrag, acc[mt][nt], 0, 0, 0);
    }

    __syncthreads();   // all reads done before next stage overwrites tile
  }

  // ---- epilogue: D row = mt*16 + 4*lg + j, col = colw + nt*16 + fr ----
  if constexpr (ATOMIC) {
    #pragma unroll
    for (int mt = 0; mt < 4; ++mt)
      #pragma unroll
      for (int nt = 0; nt < 2; ++nt)
        #pragma unroll
        for (int j = 0; j < 4; ++j)
          atomicAdd(out + (size_t)(mt * 16 + 4 * lg + j) * N_ + n0 + colw +
                        nt * 16 + fr,
                    acc[mt][nt][j]);
  } else {
    unsigned short* Pb = P + (size_t)(cb * SB + sb) * M_ * BN;
    #pragma unroll
    for (int mt = 0; mt < 4; ++mt)
      #pragma unroll
      for (int nt = 0; nt < 2; ++nt)
        #pragma unroll
        for (int j = 0; j < 4; ++j)
          Pb[(mt * 16 + 4 * lg + j) * BN + colw + nt * 16 + fr] =
              bf16_1(acc[mt][nt][j]);
  }
}

// Sum 16 bf16 partials -> f32 out. 688 blocks x 256 thr, 4 outputs/thread.
__global__ __launch_bounds__(256) void reduce_kernel(
    const unsigned short* __restrict__ P, float* __restrict__ out) {
  const int flat = blockIdx.x * 256 + threadIdx.x;  // 0 .. 176127
  const int cb = flat >> 12;
  const int r  = flat & 4095;
  const int m  = r >> 6;
  const int cq = (r & 63) * 4;
  const unsigned short* p = P + ((size_t)cb * SB * M_ + m) * BN + cq;
  float s0 = 0.f, s1 = 0.f, s2 = 0.f, s3 = 0.f;
  #pragma unroll
  for (int sb = 0; sb < SB; ++sb) {
    ushort4v v = *reinterpret_cast<const ushort4v*>(p + (size_t)sb * M_ * BN);
    s0 += __builtin_bit_cast(float, (unsigned)v[0] << 16);
    s1 += __builtin_bit_cast(float, (unsigned)v[1] << 16);
    s2 += __builtin_bit_cast(float, (unsigned)v[2] << 16);
    s3 += __builtin_bit_cast(float, (unsigned)v[3] << 16);
  }
  float4v o = {s0, s1, s2, s3};
  *reinterpret_cast<float4v*>(out + (size_t)m * N_ + cb * BN + cq) = o;
}

extern "C" void kernel_launch(void* const* d_in, const int* in_sizes, int n_in,
                              void* d_out, int out_size, void* d_ws, size_t ws_size,
                              hipStream_t stream) {
  const float* A = (const float*)d_in[0];
  const int*   q = (const int*)d_in[1];
  const float* s = (const float*)d_in[2];
  float* out = (float*)d_out;

  const size_t apBytes = (size_t)M_ * K_ * sizeof(short);              // 512 KB
  const size_t pElems  = (size_t)CB * SB * M_ * BN;                    // 11.3M
  const size_t needFull = apBytes + pElems * sizeof(unsigned short);   // ~23 MB

  if (ws_size >= needFull) {
    short* Ap = (short*)d_ws;
    unsigned short* P = (unsigned short*)((char*)d_ws + apBytes);
    hipLaunchKernelGGL(cvtA_kernel, dim3((M_ * K_) / 1024), dim3(256), 0,
                       stream, A, (unsigned*)Ap);
    hipLaunchKernelGGL((dq_gemm_kernel<true, false>), dim3(CB * SB), dim3(512),
                       0, stream, q, s, Ap, A, P, out);
    hipLaunchKernelGGL(reduce_kernel, dim3(688), dim3(256), 0, stream, P, out);
  } else if (ws_size >= apBytes) {
    short* Ap = (short*)d_ws;
    hipMemsetAsync(d_out, 0, (size_t)M_ * N_ * sizeof(float), stream);
    hipLaunchKernelGGL(cvtA_kernel, dim3((M_ * K_) / 1024), dim3(256), 0,
                       stream, A, (unsigned*)Ap);
    hipLaunchKernelGGL((dq_gemm_kernel<true, true>), dim3(CB * SB), dim3(512),
                       0, stream, q, s, Ap, A, (unsigned short*)nullptr, out);
  } else {
    hipMemsetAsync(d_out, 0, (size_t)M_ * N_ * sizeof(float), stream);
    hipLaunchKernelGGL((dq_gemm_kernel<false, true>), dim3(CB * SB), dim3(512),
                       0, stream, q, s, (const short*)nullptr, A,
                       (unsigned short*)nullptr, out);
  }
}

// Round 4
// 45.052 us; speedup vs baseline: 2.6873x; 1.2215x over previous
//
// Fused 3-bit dequant GEMM: C[64,11008] = A[64,4096] @ ((q-4) * s[group])
// R4: three fixes over R3 (~4 TB/s -> target ~6 TB/s on the q stream):
//  1. A pre-packed in MFMA fragment order (Apf[kt][mt][lane][8]) — kills the
//     64-way A-gather (was ~2000 cyc/blk-step of TA occupancy), now one
//     contiguous L1-broadcast 1KB read per fragment.
//  2. LDS double-buffer 2-phase: stage tile t+1 during compute of t, one
//     barrier/step — HBM never idles during compute.
//  3. Bank-conflict-free LDS: pitch=128 ints + per-row rot=8*lg swizzle
//     applied via pre-rotated per-lane GLOBAL source (global_load_lds writes
//     linearly); read bank = fr+8lg mod 32 -> exact 2-way = free.
// Geometry: BN=128, CB=86, SB=8 k-bands (KBAND=512, 16 steps of BK=32),
// 688 blocks x 512 thr, LDS 32KB -> 4 blocks/CU (32 waves/CU).
// bf16 partials (11.3MB) in d_ws + reduce kernel. Predicted total ~40-46us.

#include <hip/hip_runtime.h>

#define K_ 4096
#define N_ 11008
#define M_ 64
#define SB 8                    // k-split factor
#define CB 86                   // column chunks of BN
#define BK 32                   // k rows per LDS tile
#define BN 128                  // columns per block
#define KBAND (K_ / SB)         // 512
#define NSTEP (KBAND / BK)      // 16

typedef __attribute__((ext_vector_type(8))) short bf16x8;
typedef __attribute__((ext_vector_type(4))) float f32x4;
typedef __attribute__((ext_vector_type(4))) unsigned uint4v;
typedef __attribute__((ext_vector_type(4))) float float4v;
typedef __attribute__((ext_vector_type(4))) unsigned short ushort4v;

static __device__ __forceinline__ unsigned rne_bits(float f) {
  unsigned u = __builtin_bit_cast(unsigned, f);
  return u + 0x7fffu + ((u >> 16) & 1u);   // bf16 in bits [31:16], RNE
}
static __device__ __forceinline__ unsigned pack_bf16(float lo, float hi) {
  return (rne_bits(hi) & 0xffff0000u) | (rne_bits(lo) >> 16);
}
static __device__ __forceinline__ unsigned short bf16_1(float f) {
  return (unsigned short)(rne_bits(f) >> 16);
}

// A (64x4096 f32) -> Apf in MFMA fragment order: Apf[kt][mt][lane] = 8 bf16
// (4 uints). kt=k/32 (128), mt=row-tile (4), lane=64. 512KB total.
__global__ __launch_bounds__(256) void cvtA_frag_kernel(
    const float* __restrict__ A, unsigned* __restrict__ Apf) {
  const int kt = blockIdx.x;          // 0..127
  const int mt = threadIdx.x >> 6;    // 0..3
  const int l  = threadIdx.x & 63;
  const int row = mt * 16 + (l & 15);
  const int kk  = kt * 32 + (l >> 4) * 8;
  const float* ap = A + (size_t)row * K_ + kk;
  uint4v b = { pack_bf16(ap[0], ap[1]), pack_bf16(ap[2], ap[3]),
               pack_bf16(ap[4], ap[5]), pack_bf16(ap[6], ap[7]) };
  *reinterpret_cast<uint4v*>(Apf + ((size_t)(kt * 4 + mt) * 64 + l) * 4) = b;
}

template <bool FROM_FRAG, bool ATOMIC>
__global__ __launch_bounds__(512, 8) void dq_gemm_kernel(
    const int* __restrict__ q, const float* __restrict__ s,
    const unsigned* __restrict__ Apf, const float* __restrict__ Af,
    unsigned short* __restrict__ P, float* __restrict__ out) {
  __shared__ int tile[2][BK * BN];    // 2 x 16KB

  const int tid = threadIdx.x;
  const int l   = tid & 63;
  const int w   = tid >> 6;           // wave 0..7 (owns 16 columns)
  const int fr  = l & 15;
  const int lg  = l >> 4;
  const int cb  = blockIdx.x % CB;    // col chunk fastest -> adjacent blocks
  const int sb  = blockIdx.x / CB;    //   cover contiguous DRAM stretches
  const int n0  = cb * BN;
  const int k0  = sb * KBAND;
  const int cw  = w * 16;

  f32x4 acc[4] = {f32x4{0,0,0,0}, f32x4{0,0,0,0}, f32x4{0,0,0,0}, f32x4{0,0,0,0}};

  // stage [BK][BN] q tile; per-row rotation rot=8*((row>>3)&3) applied by
  // pre-rotating the per-lane global source (LDS dest stays linear).
  auto stage = [&](int buf, int kst) {
    #pragma unroll
    for (int i = 0; i < 2; ++i) {
      const int rbase = w * 4 + i * 2;             // wave-uniform row pair
      const int row   = rbase + (l >> 5);
      const int rot   = ((row >> 3) & 3) * 8;
      const int c4    = (4 * l) & 127;             // lane's LDS col (ints)
      const int src   = (c4 - rot) & 127;          // pre-rotated source col
      const int* gp   = q + (size_t)(kst + row) * N_ + n0 + src;
      __builtin_amdgcn_global_load_lds(
          (const __attribute__((address_space(1))) unsigned*)gp,
          (__attribute__((address_space(3))) unsigned*)&tile[buf][rbase * BN],
          16, 0, 0);
    }
  };

  auto compute = [&](int buf, int kst) {
    const int g = kst >> 6;
    const float sc = s[(size_t)g * N_ + n0 + cw + fr];
    const float sn = -4.0f * sc;                   // fma(q, s, -4s)

    bf16x8 af[4];
    #pragma unroll
    for (int mt = 0; mt < 4; ++mt) {
      if constexpr (FROM_FRAG) {
        af[mt] = *reinterpret_cast<const bf16x8*>(
            Apf + ((size_t)((kst >> 5) * 4 + mt) * 64 + l) * 4);
      } else {
        const float* ap = Af + (size_t)(mt * 16 + fr) * K_ + kst + 8 * lg;
        float4v v0 = *reinterpret_cast<const float4v*>(ap);
        float4v v1 = *reinterpret_cast<const float4v*>(ap + 4);
        uint4v b = { pack_bf16(v0[0], v0[1]), pack_bf16(v0[2], v0[3]),
                     pack_bf16(v1[0], v1[1]), pack_bf16(v1[2], v1[3]) };
        af[mt] = __builtin_bit_cast(bf16x8, b);
      }
    }

    const int rot = 8 * lg;                        // same rot for rows 8lg..8lg+7
    const int ci  = (cw + fr + rot) & 127;         // swizzled LDS col
    unsigned pk[4];
    #pragma unroll
    for (int p = 0; p < 4; ++p) {
      const int r0 = 8 * lg + 2 * p;
      const int c0 = tile[buf][r0 * BN + ci];
      const int c1 = tile[buf][(r0 + 1) * BN + ci];
      pk[p] = pack_bf16(fmaf((float)c0, sc, sn), fmaf((float)c1, sc, sn));
    }
    uint4v bv = {pk[0], pk[1], pk[2], pk[3]};
    const bf16x8 bfrag = __builtin_bit_cast(bf16x8, bv);
    #pragma unroll
    for (int mt = 0; mt < 4; ++mt)
      acc[mt] = __builtin_amdgcn_mfma_f32_16x16x32_bf16(af[mt], bfrag, acc[mt],
                                                        0, 0, 0);
  };

  // ---- K loop: double-buffered, one barrier per step ----
  stage(0, k0);
  __syncthreads();
  for (int st = 0; st < NSTEP; ++st) {
    const int kst = k0 + st * BK;
    if (st + 1 < NSTEP) stage((st + 1) & 1, kst + BK);
    compute(st & 1, kst);
    __syncthreads();   // drains staged loads; guards buffer reuse
  }

  // ---- epilogue: D row = mt*16 + 4*lg + j, col = cw + fr ----
  if constexpr (ATOMIC) {
    #pragma unroll
    for (int mt = 0; mt < 4; ++mt)
      #pragma unroll
      for (int j = 0; j < 4; ++j)
        atomicAdd(out + (size_t)(mt * 16 + 4 * lg + j) * N_ + n0 + cw + fr,
                  acc[mt][j]);
  } else {
    unsigned short* Pb = P + (size_t)(cb * SB + sb) * M_ * BN;
    #pragma unroll
    for (int mt = 0; mt < 4; ++mt)
      #pragma unroll
      for (int j = 0; j < 4; ++j)
        Pb[(mt * 16 + 4 * lg + j) * BN + cw + fr] = bf16_1(acc[mt][j]);
  }
}

// Sum SB bf16 partials -> f32 out. 688 blocks x 256 thr, 4 outputs/thread.
__global__ __launch_bounds__(256) void reduce_kernel(
    const unsigned short* __restrict__ P, float* __restrict__ out) {
  const int flat = blockIdx.x * 256 + threadIdx.x;  // 0 .. 176127
  const int cb = flat >> 11;                        // / 2048
  const int r  = flat & 2047;
  const int m  = r >> 5;
  const int cq = (r & 31) * 4;
  const unsigned short* p = P + ((size_t)cb * SB * M_ + m) * BN + cq;
  float s0 = 0.f, s1 = 0.f, s2 = 0.f, s3 = 0.f;
  #pragma unroll
  for (int sb = 0; sb < SB; ++sb) {
    ushort4v v = *reinterpret_cast<const ushort4v*>(p + (size_t)sb * M_ * BN);
    s0 += __builtin_bit_cast(float, (unsigned)v[0] << 16);
    s1 += __builtin_bit_cast(float, (unsigned)v[1] << 16);
    s2 += __builtin_bit_cast(float, (unsigned)v[2] << 16);
    s3 += __builtin_bit_cast(float, (unsigned)v[3] << 16);
  }
  float4v o = {s0, s1, s2, s3};
  *reinterpret_cast<float4v*>(out + (size_t)m * N_ + cb * BN + cq) = o;
}

extern "C" void kernel_launch(void* const* d_in, const int* in_sizes, int n_in,
                              void* d_out, int out_size, void* d_ws, size_t ws_size,
                              hipStream_t stream) {
  const float* A = (const float*)d_in[0];
  const int*   q = (const int*)d_in[1];
  const float* s = (const float*)d_in[2];
  float* out = (float*)d_out;

  const size_t apBytes = (size_t)128 * 4 * 64 * 16;                 // 512 KB
  const size_t pBytes  = (size_t)CB * SB * M_ * BN * sizeof(unsigned short);
  const size_t needFull = apBytes + pBytes;                         // ~11.8 MB

  if (ws_size >= needFull) {
    unsigned* Apf = (unsigned*)d_ws;
    unsigned short* P = (unsigned short*)((char*)d_ws + apBytes);
    hipLaunchKernelGGL(cvtA_frag_kernel, dim3(128), dim3(256), 0, stream,
                       A, Apf);
    hipLaunchKernelGGL((dq_gemm_kernel<true, false>), dim3(CB * SB), dim3(512),
                       0, stream, q, s, Apf, A, P, out);
    hipLaunchKernelGGL(reduce_kernel, dim3(688), dim3(256), 0, stream, P, out);
  } else if (ws_size >= apBytes) {
    unsigned* Apf = (unsigned*)d_ws;
    hipMemsetAsync(d_out, 0, (size_t)M_ * N_ * sizeof(float), stream);
    hipLaunchKernelGGL(cvtA_frag_kernel, dim3(128), dim3(256), 0, stream,
                       A, Apf);
    hipLaunchKernelGGL((dq_gemm_kernel<true, true>), dim3(CB * SB), dim3(512),
                       0, stream, q, s, Apf, A, (unsigned short*)nullptr, out);
  } else {
    hipMemsetAsync(d_out, 0, (size_t)M_ * N_ * sizeof(float), stream);
    hipLaunchKernelGGL((dq_gemm_kernel<false, true>), dim3(CB * SB), dim3(512),
                       0, stream, q, s, (const unsigned*)nullptr, A,
                       (unsigned short*)nullptr, out);
  }
}